// Round 4
// baseline (212.614 us; speedup 1.0000x reference)
//
#include <hip/hip_runtime.h>
#include <hip/hip_bf16.h>
#include <math.h>

#define B_   8
#define N_   1024
#define FIN  128
#define FOUT 128
#define H_   8
#define NEG  0.2f

typedef __attribute__((ext_vector_type(4))) float f32x4;
typedef __attribute__((ext_vector_type(8))) short s16x8;

static __device__ __forceinline__ unsigned short f2bf(float f) {
    unsigned int u = __float_as_uint(f);
    unsigned int r = (u + 0x7fffu + ((u >> 16) & 1u)) >> 16;   // RNE
    return (unsigned short)r;
}

// ---------------- K0: pack adj into bitmask (1024x1024 bits = 128 KB) ----------------
__global__ __launch_bounds__(256) void k_pack(const int* __restrict__ adj,
                                              unsigned int* __restrict__ bits) {
    int base = blockIdx.x * 256 + threadIdx.x;
    unsigned long long m = __ballot(adj[base] != 0);
    int lane = threadIdx.x & 63;
    if (lane == 0) {
        int widx = base >> 5;
        bits[widx]     = (unsigned int)m;
        bits[widx + 1] = (unsigned int)(m >> 32);
    }
}

// ---------------- K1: h' GEMM + transpose-to-bf16 + s1/s2 epilogue ----------------
// grid (BN/64, H), block 256
union SmemK1 {
    struct { float ht[64][32]; float wt[32][128]; } s;   // 24 KB
    float tr[64][129];                                    // 33 KB (padded transpose buf)
};

__global__ __launch_bounds__(256) void k_hprime(const float* __restrict__ hsrc,
                                                const float* __restrict__ W,
                                                const float* __restrict__ a,
                                                unsigned short* __restrict__ hpT,
                                                float* __restrict__ s1,
                                                float* __restrict__ s2T) {
    __shared__ SmemK1 sm;
    const int t   = threadIdx.x;
    const int bn0 = blockIdx.x * 64;
    const int hd  = blockIdx.y;
    const int tx = t & 31, ty = t >> 5;
    const int c0 = tx * 4, r0 = ty * 8;
    float acc[8][4];
#pragma unroll
    for (int k = 0; k < 8; ++k) { acc[k][0]=0.f; acc[k][1]=0.f; acc[k][2]=0.f; acc[k][3]=0.f; }

    for (int k0 = 0; k0 < FIN; k0 += 32) {
#pragma unroll
        for (int q = 0; q < 2; ++q) {
            int idx = t + q * 256;
            int r = idx >> 3, kq = idx & 7;
            *(float4*)&sm.s.ht[r][kq * 4] =
                *(const float4*)&hsrc[(size_t)(bn0 + r) * FIN + k0 + kq * 4];
        }
#pragma unroll
        for (int q = 0; q < 4; ++q) {
            int idx = t + q * 256;
            int kk = idx >> 5, c4 = idx & 31;
            *(float4*)&sm.s.wt[kk][c4 * 4] =
                *(const float4*)&W[((size_t)hd * FIN + k0 + kk) * FOUT + c4 * 4];
        }
        __syncthreads();
#pragma unroll 8
        for (int kk = 0; kk < 32; ++kk) {
            float4 wv = *(float4*)&sm.s.wt[kk][c0];
#pragma unroll
            for (int k = 0; k < 8; ++k) {
                float av = sm.s.ht[r0 + k][kk];
                acc[k][0] += av * wv.x; acc[k][1] += av * wv.y;
                acc[k][2] += av * wv.z; acc[k][3] += av * wv.w;
            }
        }
        __syncthreads();
    }
    // stage f32 result into padded transpose buffer
#pragma unroll
    for (int k = 0; k < 8; ++k) {
        sm.tr[r0 + k][c0 + 0] = acc[k][0];
        sm.tr[r0 + k][c0 + 1] = acc[k][1];
        sm.tr[r0 + k][c0 + 2] = acc[k][2];
        sm.tr[r0 + k][c0 + 3] = acc[k][3];
    }
    __syncthreads();

    // transposed bf16 write: thread t handles f = t>>1, n-segment (t&1)*32..+31
    {
        const int f   = t >> 1;
        const int seg = (t & 1) * 32;
        const int b   = bn0 >> 10;
        const int n0  = bn0 & 1023;
        unsigned short* dst = hpT + (((size_t)(b * H_ + hd) * FOUT + f) * N_) + n0 + seg;
#pragma unroll
        for (int c = 0; c < 4; ++c) {
            s16x8 v;
#pragma unroll
            for (int u = 0; u < 8; ++u)
                v[u] = (short)f2bf(sm.tr[seg + c * 8 + u][f]);
            *(s16x8*)(dst + c * 8) = v;
        }
    }
    // s1/s2 from exact f32 h': 4 threads per row, 32 f each, shfl reduce
    {
        const int row = t >> 2, f0 = (t & 3) * 32;
        const float* a1 = a + (size_t)hd * 2 * FOUT;
        const float* a2 = a1 + FOUT;
        float v1 = 0.f, v2 = 0.f;
#pragma unroll 8
        for (int fi = 0; fi < 32; ++fi) {
            float hv = sm.tr[row][f0 + fi];
            v1 += hv * a1[f0 + fi];
            v2 += hv * a2[f0 + fi];
        }
        v1 += __shfl_xor(v1, 1); v1 += __shfl_xor(v1, 2);
        v2 += __shfl_xor(v2, 1); v2 += __shfl_xor(v2, 2);
        if ((t & 3) == 0) {
            int bn = bn0 + row;
            s1[(size_t)bn * 8 + hd]          = v1;
            s2T[(size_t)hd * (B_ * N_) + bn] = v2;
        }
    }
}

// ---------------- K2: fused P-gen + MFMA PV, 32-row i-tiles for occupancy ----------------
// grid (N/32, H, B), block 256 (4 waves, each 16 rows x 64 cols)
__global__ __launch_bounds__(256, 8) void k_pv2(const unsigned short* __restrict__ hpT,
                                                const float* __restrict__ s1,
                                                const float* __restrict__ s2T,
                                                const unsigned int* __restrict__ adjbits,
                                                const float* __restrict__ bias,
                                                float* __restrict__ out) {
    __shared__ __align__(16) unsigned short P[2][32][72];   // 9.2 KB double-buffered
    __shared__ float Zl[32];
    const int t    = threadIdx.x;
    const int lane = t & 63;
    const int wave = t >> 6;
    const int i0 = blockIdx.x * 32;
    const int hd = blockIdx.y;
    const int b  = blockIdx.z;

    // P-gen assignment: one row per 8 threads, 8 consecutive j each
    const int prow = t >> 3;          // 0..31
    const int pj0  = (t & 7) * 8;     // 0,8,..,56
    const int gi   = (b << 10) + i0 + prow;
    const float s1v = s1[(size_t)gi * 8 + hd];
    const unsigned int* abr = adjbits + (size_t)(i0 + prow) * 32;
    const float* bias_row   = bias + (size_t)(i0 + prow) * N_;
    const float* s2p        = s2T + (size_t)hd * (B_ * N_) + (b << 10);

    // wave output tile: 16 rows x 64 cols
    const int wr = (wave & 1) * 16;
    const int wc = (wave >> 1) * 64;
    const int arow = wr + (lane & 15);
    const int koff = (lane >> 4) * 8;
    const unsigned short* bbase =
        hpT + ((size_t)(b * H_ + hd) * FOUT + wc + (lane & 15)) * N_ + koff;

    f32x4 acc[4];
#pragma unroll
    for (int j = 0; j < 4; ++j) acc[j] = (f32x4){0.f, 0.f, 0.f, 0.f};
    float z_acc = 0.f;

    auto load_it = [&](int j0, unsigned int& aw_, float4 (&bv_)[2], float4 (&sv_)[2]) {
        aw_ = (abr[(j0 + pj0) >> 5] >> (pj0 & 31)) & 0xffu;
#pragma unroll
        for (int q = 0; q < 2; ++q) {
            bv_[q] = *(const float4*)&bias_row[j0 + pj0 + q * 4];
            sv_[q] = *(const float4*)&s2p[j0 + pj0 + q * 4];
        }
    };
    auto comp_store = [&](int buf, unsigned int aw_, float4 (&bv_)[2], float4 (&sv_)[2]) {
#pragma unroll
        for (int q = 0; q < 2; ++q) {
            float x0 = s1v + sv_[q].x; x0 = (x0 > 0.f ? x0 : NEG * x0) + bv_[q].x;
            float x1 = s1v + sv_[q].y; x1 = (x1 > 0.f ? x1 : NEG * x1) + bv_[q].y;
            float x2 = s1v + sv_[q].z; x2 = (x2 > 0.f ? x2 : NEG * x2) + bv_[q].z;
            float x3 = s1v + sv_[q].w; x3 = (x3 > 0.f ? x3 : NEG * x3) + bv_[q].w;
            float p0 = (aw_ >> (q * 4 + 0)) & 1 ? __expf(x0) : 0.f;
            float p1 = (aw_ >> (q * 4 + 1)) & 1 ? __expf(x1) : 0.f;
            float p2 = (aw_ >> (q * 4 + 2)) & 1 ? __expf(x2) : 0.f;
            float p3 = (aw_ >> (q * 4 + 3)) & 1 ? __expf(x3) : 0.f;
            z_acc += (p0 + p1) + (p2 + p3);
            *(ushort4*)&P[buf][prow][pj0 + q * 4] =
                make_ushort4(f2bf(p0), f2bf(p1), f2bf(p2), f2bf(p3));
        }
    };

    // prologue: build P[0]
    {
        unsigned int aw; float4 bv[2], sv[2];
        load_it(0, aw, bv, sv);
        comp_store(0, aw, bv, sv);
    }
    __syncthreads();

    for (int it = 0; it < 16; ++it) {
        const int cur = it & 1;
        const int j0  = it * 64;
        unsigned int naw; float4 nbv[2], nsv[2];
        if (it < 15) load_it(j0 + 64, naw, nbv, nsv);   // loads overlap MFMA below
        // ---- MFMA phase on P[cur]: A from LDS, B from global (L2-resident)
#pragma unroll
        for (int kw = 0; kw < 2; ++kw) {
            s16x8 a0 = *(const s16x8*)&P[cur][arow][kw * 32 + koff];
            const unsigned short* bp = bbase + j0 + kw * 32;
#pragma unroll
            for (int fc = 0; fc < 4; ++fc) {
                s16x8 bf = *(const s16x8*)(bp + (size_t)fc * 16 * N_);
                acc[fc] = __builtin_amdgcn_mfma_f32_16x16x32_bf16(a0, bf, acc[fc], 0, 0, 0);
            }
        }
        // ---- build next P tile while MFMAs drain
        if (it < 15) comp_store(cur ^ 1, naw, nbv, nsv);
        __syncthreads();
    }

    // Z: reduce 8 lanes per row (lanes grouped consecutively within a wave)
    float z = z_acc;
    z += __shfl_xor(z, 1); z += __shfl_xor(z, 2); z += __shfl_xor(z, 4);
    if ((t & 7) == 0) Zl[prow] = 0.125f / z;   // folds softmax norm + head-mean
    __syncthreads();

    // epilogue: C/D layout col=lane&15, row=(lane>>4)*4+reg
#pragma unroll
    for (int r = 0; r < 4; ++r) {
        const int il = wr + (lane >> 4) * 4 + r;
        const float sc = Zl[il];
        float* op = out + ((size_t)((b << 10) + i0 + il)) * FOUT + wc + (lane & 15);
#pragma unroll
        for (int fc = 0; fc < 4; ++fc)
            unsafeAtomicAdd(op + fc * 16, acc[fc][r] * sc);
    }
}

extern "C" void kernel_launch(void* const* d_in, const int* in_sizes, int n_in,
                              void* d_out, int out_size, void* d_ws, size_t ws_size,
                              hipStream_t stream) {
    const float* hsrc = (const float*)d_in[0];
    const int*   adj  = (const int*)d_in[1];
    const float* bias = (const float*)d_in[2];
    const float* W    = (const float*)d_in[3];
    const float* a    = (const float*)d_in[4];
    float* out = (float*)d_out;

    char* ws = (char*)d_ws;
    unsigned short* hpT = (unsigned short*)ws;                 // 8*8*128*1024 bf16 = 16 MB
    float* s1  = (float*)(ws + 16777216);                      // 64K f32 = 256 KB
    float* s2T = s1 + 65536;                                   // 256 KB
    unsigned int* adjbits = (unsigned int*)(s2T + 65536);      // 128 KB

    hipMemsetAsync(d_out, 0, (size_t)out_size * sizeof(float), stream);
    k_pack<<<dim3(N_ * N_ / 256), 256, 0, stream>>>(adj, adjbits);
    k_hprime<<<dim3(B_ * N_ / 64, H_), 256, 0, stream>>>(hsrc, W, a, hpT, s1, s2T);
    k_pv2<<<dim3(N_ / 32, H_, B_), 256, 0, stream>>>(hpT, s1, s2T, adjbits, bias, out);
}

// Round 5
// 131.810 us; speedup vs baseline: 1.6130x; 1.6130x over previous
//
#include <hip/hip_runtime.h>
#include <hip/hip_bf16.h>
#include <math.h>

#define B_   8
#define N_   1024
#define FIN  128
#define FOUT 128
#define H_   8
#define NEG  0.2f

typedef __attribute__((ext_vector_type(4))) float f32x4;
typedef __attribute__((ext_vector_type(8))) short s16x8;

static __device__ __forceinline__ unsigned short f2bf(float f) {
    unsigned int u = __float_as_uint(f);
    unsigned int r = (u + 0x7fffu + ((u >> 16) & 1u)) >> 16;   // RNE
    return (unsigned short)r;
}

// ---------------- K0: pack adj into bitmask (1024x1024 bits = 128 KB) ----------------
__global__ __launch_bounds__(256) void k_pack(const int* __restrict__ adj,
                                              unsigned int* __restrict__ bits) {
    int base = blockIdx.x * 256 + threadIdx.x;
    unsigned long long m = __ballot(adj[base] != 0);
    int lane = threadIdx.x & 63;
    if (lane == 0) {
        int widx = base >> 5;
        bits[widx]     = (unsigned int)m;
        bits[widx + 1] = (unsigned int)(m >> 32);
    }
}

// ---------------- K1: h' GEMM + transpose-to-bf16 + s1/s2 epilogue ----------------
// grid (BN/64, H), block 256
union SmemK1 {
    struct { float ht[64][32]; float wt[32][128]; } s;   // 24 KB
    float tr[64][129];                                    // 33 KB (padded transpose buf)
};

__global__ __launch_bounds__(256) void k_hprime(const float* __restrict__ hsrc,
                                                const float* __restrict__ W,
                                                const float* __restrict__ a,
                                                unsigned short* __restrict__ hpT,
                                                float* __restrict__ s1,
                                                float* __restrict__ s2T) {
    __shared__ SmemK1 sm;
    const int t   = threadIdx.x;
    const int bn0 = blockIdx.x * 64;
    const int hd  = blockIdx.y;
    const int tx = t & 31, ty = t >> 5;
    const int c0 = tx * 4, r0 = ty * 8;
    float acc[8][4];
#pragma unroll
    for (int k = 0; k < 8; ++k) { acc[k][0]=0.f; acc[k][1]=0.f; acc[k][2]=0.f; acc[k][3]=0.f; }

    for (int k0 = 0; k0 < FIN; k0 += 32) {
#pragma unroll
        for (int q = 0; q < 2; ++q) {
            int idx = t + q * 256;
            int r = idx >> 3, kq = idx & 7;
            *(float4*)&sm.s.ht[r][kq * 4] =
                *(const float4*)&hsrc[(size_t)(bn0 + r) * FIN + k0 + kq * 4];
        }
#pragma unroll
        for (int q = 0; q < 4; ++q) {
            int idx = t + q * 256;
            int kk = idx >> 5, c4 = idx & 31;
            *(float4*)&sm.s.wt[kk][c4 * 4] =
                *(const float4*)&W[((size_t)hd * FIN + k0 + kk) * FOUT + c4 * 4];
        }
        __syncthreads();
#pragma unroll 8
        for (int kk = 0; kk < 32; ++kk) {
            float4 wv = *(float4*)&sm.s.wt[kk][c0];
#pragma unroll
            for (int k = 0; k < 8; ++k) {
                float av = sm.s.ht[r0 + k][kk];
                acc[k][0] += av * wv.x; acc[k][1] += av * wv.y;
                acc[k][2] += av * wv.z; acc[k][3] += av * wv.w;
            }
        }
        __syncthreads();
    }
    // stage f32 result into padded transpose buffer
#pragma unroll
    for (int k = 0; k < 8; ++k) {
        sm.tr[r0 + k][c0 + 0] = acc[k][0];
        sm.tr[r0 + k][c0 + 1] = acc[k][1];
        sm.tr[r0 + k][c0 + 2] = acc[k][2];
        sm.tr[r0 + k][c0 + 3] = acc[k][3];
    }
    __syncthreads();

    // transposed bf16 write: thread t handles f = t>>1, n-segment (t&1)*32..+31
    {
        const int f   = t >> 1;
        const int seg = (t & 1) * 32;
        const int b   = bn0 >> 10;
        const int n0  = bn0 & 1023;
        unsigned short* dst = hpT + (((size_t)(b * H_ + hd) * FOUT + f) * N_) + n0 + seg;
#pragma unroll
        for (int c = 0; c < 4; ++c) {
            s16x8 v;
#pragma unroll
            for (int u = 0; u < 8; ++u)
                v[u] = (short)f2bf(sm.tr[seg + c * 8 + u][f]);
            *(s16x8*)(dst + c * 8) = v;
        }
    }
    // s1/s2 from exact f32 h': 4 threads per row, 32 f each, shfl reduce
    {
        const int row = t >> 2, f0 = (t & 3) * 32;
        const float* a1 = a + (size_t)hd * 2 * FOUT;
        const float* a2 = a1 + FOUT;
        float v1 = 0.f, v2 = 0.f;
#pragma unroll 8
        for (int fi = 0; fi < 32; ++fi) {
            float hv = sm.tr[row][f0 + fi];
            v1 += hv * a1[f0 + fi];
            v2 += hv * a2[f0 + fi];
        }
        v1 += __shfl_xor(v1, 1); v1 += __shfl_xor(v1, 2);
        v2 += __shfl_xor(v2, 1); v2 += __shfl_xor(v2, 2);
        if ((t & 3) == 0) {
            int bn = bn0 + row;
            s1[(size_t)bn * 8 + hd]          = v1;
            s2T[(size_t)hd * (B_ * N_) + bn] = v2;
        }
    }
}

// ---------------- K2: fused P-gen + MFMA PV, LDS-staged B-tile (line-dense loads) ----
// grid (N/64, H, B), block 256 (4 waves, each 32 rows x 64 cols)
__global__ __launch_bounds__(256, 4) void k_pv2(const unsigned short* __restrict__ hpT,
                                                const float* __restrict__ s1,
                                                const float* __restrict__ s2T,
                                                const unsigned int* __restrict__ adjbits,
                                                const float* __restrict__ bias,
                                                float* __restrict__ out) {
    __shared__ __align__(16) unsigned short P[64][72];    // 9.2 KB
    __shared__ __align__(16) unsigned short Bl[128 * 64]; // 16 KB, XOR-swizzled chunks
    __shared__ float Zl[64];
    const int t    = threadIdx.x;
    const int lane = t & 63;
    const int wave = t >> 6;
    const int i0 = blockIdx.x * 64;
    const int hd = blockIdx.y;
    const int b  = blockIdx.z;

    // P-gen assignment: one row per 4 threads, 16 consecutive j each
    const int prow = t >> 2;          // 0..63
    const int pj0  = (t & 3) * 16;
    const int gi   = (b << 10) + i0 + prow;
    const float s1v = s1[(size_t)gi * 8 + hd];
    const unsigned int* abr = adjbits + (size_t)(i0 + prow) * 32;
    const float* bias_row   = bias + (size_t)(i0 + prow) * N_;
    const float* s2p        = s2T + (size_t)hd * (B_ * N_) + (b << 10);

    // B staging: thread t covers chunk ids {q*256+t}, id -> (f-row id>>3, chunk id&7)
    const unsigned short* hpS = hpT + (size_t)(b * H_ + hd) * FOUT * N_;
    const int brow = t >> 3;          // base f-row for q=0 (rows 0..31)
    const int bc   = t & 7;           // 16B chunk within 128B j-row

    // wave output tile: 32 rows x 64 cols
    const int wr = (wave & 1) * 32;
    const int wc = (wave >> 1) * 64;
    const int arow0 = wr + (lane & 15);
    const int koff  = (lane >> 4) * 8;

    f32x4 acc[2][4];
#pragma unroll
    for (int i = 0; i < 2; ++i)
#pragma unroll
        for (int j = 0; j < 4; ++j) acc[i][j] = (f32x4){0.f, 0.f, 0.f, 0.f};
    float z_acc = 0.f;

    unsigned int aw;
    float4 bv[4], sv[4];
    s16x8 Breg[4];

    auto load_it = [&](int j0) {
        aw = (abr[(j0 + pj0) >> 5] >> (pj0 & 16)) & 0xffffu;
#pragma unroll
        for (int q = 0; q < 4; ++q) {
            bv[q] = *(const float4*)&bias_row[j0 + pj0 + q * 4];
            sv[q] = *(const float4*)&s2p[j0 + pj0 + q * 4];
        }
    };
    auto bload = [&](int j0) {
#pragma unroll
        for (int q = 0; q < 4; ++q)
            Breg[q] = *(const s16x8*)&hpS[(size_t)(brow + q * 32) * N_ + j0 + bc * 8];
    };
    auto phaseA = [&]() {
        // swizzled LDS write of B tile
#pragma unroll
        for (int q = 0; q < 4; ++q) {
            int row = brow + q * 32;
            *(s16x8*)&Bl[row * 64 + ((bc ^ (row & 7)) * 8)] = Breg[q];
        }
        // P-gen + Z
#pragma unroll
        for (int q = 0; q < 4; ++q) {
            float x0 = s1v + sv[q].x; x0 = (x0 > 0.f ? x0 : NEG * x0) + bv[q].x;
            float x1 = s1v + sv[q].y; x1 = (x1 > 0.f ? x1 : NEG * x1) + bv[q].y;
            float x2 = s1v + sv[q].z; x2 = (x2 > 0.f ? x2 : NEG * x2) + bv[q].z;
            float x3 = s1v + sv[q].w; x3 = (x3 > 0.f ? x3 : NEG * x3) + bv[q].w;
            float p0 = (aw >> (q * 4 + 0)) & 1 ? __expf(x0) : 0.f;
            float p1 = (aw >> (q * 4 + 1)) & 1 ? __expf(x1) : 0.f;
            float p2 = (aw >> (q * 4 + 2)) & 1 ? __expf(x2) : 0.f;
            float p3 = (aw >> (q * 4 + 3)) & 1 ? __expf(x3) : 0.f;
            z_acc += (p0 + p1) + (p2 + p3);
            *(ushort4*)&P[prow][pj0 + q * 4] =
                make_ushort4(f2bf(p0), f2bf(p1), f2bf(p2), f2bf(p3));
        }
    };

    // prologue
    bload(0);
    load_it(0);

    for (int it = 0; it < 16; ++it) {
        const int j0 = it * 64;
        phaseA();                       // LDS writes of B + P (consumes regs)
        __syncthreads();
        if (it < 15) { bload(j0 + 64); load_it(j0 + 64); }   // overlap with MFMA below
        // ---- MFMA phase: A (P) and B (h') fragments from LDS
#pragma unroll
        for (int kw = 0; kw < 2; ++kw) {
            s16x8 a0 = *(const s16x8*)&P[arow0][kw * 32 + koff];
            s16x8 a1 = *(const s16x8*)&P[arow0 + 16][kw * 32 + koff];
#pragma unroll
            for (int fc = 0; fc < 4; ++fc) {
                const int r = wc + fc * 16 + (lane & 15);
                const int chunk = (lane >> 4) + kw * 4;
                s16x8 bf = *(const s16x8*)&Bl[r * 64 + ((chunk ^ (r & 7)) * 8)];
                acc[0][fc] = __builtin_amdgcn_mfma_f32_16x16x32_bf16(a0, bf, acc[0][fc], 0, 0, 0);
                acc[1][fc] = __builtin_amdgcn_mfma_f32_16x16x32_bf16(a1, bf, acc[1][fc], 0, 0, 0);
            }
        }
        __syncthreads();
    }

    // Z: reduce 4 lanes per row (lanes grouped consecutively)
    float z2 = z_acc + __shfl_xor(z_acc, 1);
    float z4 = z2 + __shfl_xor(z2, 2);
    if ((lane & 3) == 0) Zl[prow] = 0.125f / z4;   // folds softmax norm + head-mean
    __syncthreads();

    // epilogue: C/D layout col=lane&15, row=(lane>>4)*4+reg
#pragma unroll
    for (int fr = 0; fr < 2; ++fr) {
#pragma unroll
        for (int r = 0; r < 4; ++r) {
            const int il = wr + fr * 16 + (lane >> 4) * 4 + r;
            const float sc = Zl[il];
            float* op = out + ((size_t)((b << 10) + i0 + il)) * FOUT + wc + (lane & 15);
#pragma unroll
            for (int fc = 0; fc < 4; ++fc)
                unsafeAtomicAdd(op + fc * 16, acc[fr][fc][r] * sc);
        }
    }
}

extern "C" void kernel_launch(void* const* d_in, const int* in_sizes, int n_in,
                              void* d_out, int out_size, void* d_ws, size_t ws_size,
                              hipStream_t stream) {
    const float* hsrc = (const float*)d_in[0];
    const int*   adj  = (const int*)d_in[1];
    const float* bias = (const float*)d_in[2];
    const float* W    = (const float*)d_in[3];
    const float* a    = (const float*)d_in[4];
    float* out = (float*)d_out;

    char* ws = (char*)d_ws;
    unsigned short* hpT = (unsigned short*)ws;                 // 8*8*128*1024 bf16 = 16 MB
    float* s1  = (float*)(ws + 16777216);                      // 64K f32 = 256 KB
    float* s2T = s1 + 65536;                                   // 256 KB
    unsigned int* adjbits = (unsigned int*)(s2T + 65536);      // 128 KB

    hipMemsetAsync(d_out, 0, (size_t)out_size * sizeof(float), stream);
    k_pack<<<dim3(N_ * N_ / 256), 256, 0, stream>>>(adj, adjbits);
    k_hprime<<<dim3(B_ * N_ / 64, H_), 256, 0, stream>>>(hsrc, W, a, hpT, s1, s2T);
    k_pv2<<<dim3(N_ / 64, H_, B_), 256, 0, stream>>>(hpT, s1, s2T, adjbits, bias, out);
}

// Round 6
// 103.481 us; speedup vs baseline: 2.0546x; 1.2738x over previous
//
#include <hip/hip_runtime.h>
#include <hip/hip_bf16.h>
#include <math.h>

#define B_   8
#define N_   1024
#define FIN  128
#define FOUT 128
#define H_   8
#define NEG  0.2f

typedef __attribute__((ext_vector_type(4))) float f32x4;
typedef __attribute__((ext_vector_type(8))) short s16x8;

static __device__ __forceinline__ unsigned short f2bf(float f) {
    unsigned int u = __float_as_uint(f);
    unsigned int r = (u + 0x7fffu + ((u >> 16) & 1u)) >> 16;   // RNE
    return (unsigned short)r;
}

// ---------------- K0: pack adj into bitmask (1024x1024 bits = 128 KB) ----------------
__global__ __launch_bounds__(256) void k_pack(const int* __restrict__ adj,
                                              unsigned int* __restrict__ bits) {
    int base = blockIdx.x * 256 + threadIdx.x;
    unsigned long long m = __ballot(adj[base] != 0);
    int lane = threadIdx.x & 63;
    if (lane == 0) {
        int widx = base >> 5;
        bits[widx]     = (unsigned int)m;
        bits[widx + 1] = (unsigned int)(m >> 32);
    }
}

// ---------------- K0b: W [H][FIN][FOUT] f32  ->  WT [H][FOUT][FIN] bf16 --------------
// grid H, block 256
__global__ __launch_bounds__(256) void k_wt(const float* __restrict__ W,
                                            unsigned short* __restrict__ WT) {
    const int hd = blockIdx.x;
    const int t  = threadIdx.x;
    const int fo  = t >> 1;
    const int fi0 = (t & 1) * 64;
    const float* src = W + (size_t)hd * FIN * FOUT;
    unsigned short* dst = WT + ((size_t)hd * FOUT + fo) * FIN + fi0;
#pragma unroll
    for (int c = 0; c < 8; ++c) {
        s16x8 v;
#pragma unroll
        for (int u = 0; u < 8; ++u)
            v[u] = (short)f2bf(src[(size_t)(fi0 + c * 8 + u) * FOUT + fo]);
        *(s16x8*)(dst + c * 8) = v;
    }
}

// ---------------- K1: h' via bf16 MFMA + transpose-to-bf16 + s1/s2 epilogue ----------
// grid (BN/64, H), block 256 (4 waves, each 16 rows x 128 cols)
#define PADK 132   // shorts; 264B row stride -> balanced b128 reads
union SmemK1 {
    struct {
        unsigned short A[64 * PADK];     // 16896 B  (h tile, bf16)
        unsigned short Bm[128 * PADK];   // 33792 B  (WT tile, bf16)
    } s;                                  // 50688 B
    float tr[64 * PADK];                  // 33792 B  (C f32, [n][f] padded)
};

__global__ __launch_bounds__(256, 3) void k_hprime(const float* __restrict__ hsrc,
                                                   const unsigned short* __restrict__ WT,
                                                   const float* __restrict__ a,
                                                   unsigned short* __restrict__ hpT,
                                                   float* __restrict__ s1,
                                                   float* __restrict__ s2T) {
    __shared__ SmemK1 sm;
    const int t    = threadIdx.x;
    const int lane = t & 63;
    const int wave = t >> 6;
    const int bn0  = blockIdx.x * 64;
    const int hd   = blockIdx.y;

    // ---- stage A: h rows bn0..+63 f32 -> bf16 LDS. thread: row=t>>2, k0=(t&3)*32
    {
        const int r = t >> 2, k0 = (t & 3) * 32;
        const float* src = hsrc + (size_t)(bn0 + r) * FIN + k0;
        unsigned short* dst = &sm.s.A[r * PADK + k0];
#pragma unroll
        for (int c = 0; c < 4; ++c) {
            float4 x = *(const float4*)&src[c * 8];
            float4 y = *(const float4*)&src[c * 8 + 4];
            s16x8 v;
            v[0] = (short)f2bf(x.x); v[1] = (short)f2bf(x.y);
            v[2] = (short)f2bf(x.z); v[3] = (short)f2bf(x.w);
            v[4] = (short)f2bf(y.x); v[5] = (short)f2bf(y.y);
            v[6] = (short)f2bf(y.z); v[7] = (short)f2bf(y.w);
            *(s16x8*)(dst + c * 8) = v;
        }
    }
    // ---- stage B: WT[hd] 128x128 bf16. thread: row=t>>1, k0=(t&1)*64
    {
        const int r = t >> 1, k0 = (t & 1) * 64;
        const unsigned short* src = WT + ((size_t)hd * FOUT + r) * FIN + k0;
        unsigned short* dst = &sm.s.Bm[r * PADK + k0];
#pragma unroll
        for (int c = 0; c < 8; ++c)
            *(s16x8*)(dst + c * 8) = *(const s16x8*)(src + c * 8);
    }
    __syncthreads();

    // ---- MFMA: wave tile 16 rows x 128 cols, K=128
    const int wr   = wave * 16;
    const int arow = wr + (lane & 15);
    const int koff = (lane >> 4) * 8;
    f32x4 acc[8];
#pragma unroll
    for (int fc = 0; fc < 8; ++fc) acc[fc] = (f32x4){0.f, 0.f, 0.f, 0.f};
#pragma unroll
    for (int kk = 0; kk < 4; ++kk) {
        s16x8 av = *(const s16x8*)&sm.s.A[arow * PADK + kk * 32 + koff];
#pragma unroll
        for (int fc = 0; fc < 8; ++fc) {
            s16x8 bv = *(const s16x8*)&sm.s.Bm[(fc * 16 + (lane & 15)) * PADK + kk * 32 + koff];
            acc[fc] = __builtin_amdgcn_mfma_f32_16x16x32_bf16(av, bv, acc[fc], 0, 0, 0);
        }
    }
    __syncthreads();   // done reading A/Bm; reuse union as tr

    // ---- C -> tr[n][f] f32 (C/D layout: col=lane&15, row=(lane>>4)*4+reg)
#pragma unroll
    for (int fc = 0; fc < 8; ++fc)
#pragma unroll
        for (int r = 0; r < 4; ++r)
            sm.tr[(wr + (lane >> 4) * 4 + r) * PADK + fc * 16 + (lane & 15)] = acc[fc][r];
    __syncthreads();

    // ---- transposed bf16 write: thread t: f = t>>1, n-segment (t&1)*32..+31
    {
        const int f   = t >> 1;
        const int seg = (t & 1) * 32;
        const int b   = bn0 >> 10;
        const int n0  = bn0 & 1023;
        unsigned short* dst = hpT + (((size_t)(b * H_ + hd) * FOUT + f) * N_) + n0 + seg;
#pragma unroll
        for (int c = 0; c < 4; ++c) {
            s16x8 v;
#pragma unroll
            for (int u = 0; u < 8; ++u)
                v[u] = (short)f2bf(sm.tr[(seg + c * 8 + u) * PADK + f]);
            *(s16x8*)(dst + c * 8) = v;
        }
    }
    // ---- s1/s2 from exact f32 h': 4 threads per row, 32 f each, shfl reduce
    {
        const int row = t >> 2, f0 = (t & 3) * 32;
        const float* a1 = a + (size_t)hd * 2 * FOUT;
        const float* a2 = a1 + FOUT;
        float v1 = 0.f, v2 = 0.f;
#pragma unroll 8
        for (int fi = 0; fi < 32; ++fi) {
            float hv = sm.tr[row * PADK + f0 + fi];
            v1 += hv * a1[f0 + fi];
            v2 += hv * a2[f0 + fi];
        }
        v1 += __shfl_xor(v1, 1); v1 += __shfl_xor(v1, 2);
        v2 += __shfl_xor(v2, 1); v2 += __shfl_xor(v2, 2);
        if ((t & 3) == 0) {
            int bn = bn0 + row;
            s1[(size_t)bn * 8 + hd]          = v1;
            s2T[(size_t)hd * (B_ * N_) + bn] = v2;
        }
    }
}

// ---------------- K2: fused P-gen + MFMA PV, LDS-staged B-tile (line-dense loads) ----
// grid (N/64, H, B), block 256 (4 waves, each 32 rows x 64 cols)
__global__ __launch_bounds__(256, 4) void k_pv2(const unsigned short* __restrict__ hpT,
                                                const float* __restrict__ s1,
                                                const float* __restrict__ s2T,
                                                const unsigned int* __restrict__ adjbits,
                                                const float* __restrict__ bias,
                                                float* __restrict__ out) {
    __shared__ __align__(16) unsigned short P[64][72];    // 9.2 KB
    __shared__ __align__(16) unsigned short Bl[128 * 64]; // 16 KB, XOR-swizzled chunks
    __shared__ float Zl[64];
    const int t    = threadIdx.x;
    const int lane = t & 63;
    const int wave = t >> 6;
    const int i0 = blockIdx.x * 64;
    const int hd = blockIdx.y;
    const int b  = blockIdx.z;

    // P-gen assignment: one row per 4 threads, 16 consecutive j each
    const int prow = t >> 2;          // 0..63
    const int pj0  = (t & 3) * 16;
    const int gi   = (b << 10) + i0 + prow;
    const float s1v = s1[(size_t)gi * 8 + hd];
    const unsigned int* abr = adjbits + (size_t)(i0 + prow) * 32;
    const float* bias_row   = bias + (size_t)(i0 + prow) * N_;
    const float* s2p        = s2T + (size_t)hd * (B_ * N_) + (b << 10);

    // B staging: thread t covers chunk ids {q*256+t}, id -> (f-row id>>3, chunk id&7)
    const unsigned short* hpS = hpT + (size_t)(b * H_ + hd) * FOUT * N_;
    const int brow = t >> 3;          // base f-row for q=0 (rows 0..31)
    const int bc   = t & 7;           // 16B chunk within 128B j-row

    // wave output tile: 32 rows x 64 cols
    const int wr = (wave & 1) * 32;
    const int wc = (wave >> 1) * 64;
    const int arow0 = wr + (lane & 15);
    const int koff  = (lane >> 4) * 8;

    f32x4 acc[2][4];
#pragma unroll
    for (int i = 0; i < 2; ++i)
#pragma unroll
        for (int j = 0; j < 4; ++j) acc[i][j] = (f32x4){0.f, 0.f, 0.f, 0.f};
    float z_acc = 0.f;

    unsigned int aw;
    float4 bv[4], sv[4];
    s16x8 Breg[4];

    auto load_it = [&](int j0) {
        aw = (abr[(j0 + pj0) >> 5] >> (pj0 & 16)) & 0xffffu;
#pragma unroll
        for (int q = 0; q < 4; ++q) {
            bv[q] = *(const float4*)&bias_row[j0 + pj0 + q * 4];
            sv[q] = *(const float4*)&s2p[j0 + pj0 + q * 4];
        }
    };
    auto bload = [&](int j0) {
#pragma unroll
        for (int q = 0; q < 4; ++q)
            Breg[q] = *(const s16x8*)&hpS[(size_t)(brow + q * 32) * N_ + j0 + bc * 8];
    };
    auto phaseA = [&]() {
        // swizzled LDS write of B tile
#pragma unroll
        for (int q = 0; q < 4; ++q) {
            int row = brow + q * 32;
            *(s16x8*)&Bl[row * 64 + ((bc ^ (row & 7)) * 8)] = Breg[q];
        }
        // P-gen + Z
#pragma unroll
        for (int q = 0; q < 4; ++q) {
            float x0 = s1v + sv[q].x; x0 = (x0 > 0.f ? x0 : NEG * x0) + bv[q].x;
            float x1 = s1v + sv[q].y; x1 = (x1 > 0.f ? x1 : NEG * x1) + bv[q].y;
            float x2 = s1v + sv[q].z; x2 = (x2 > 0.f ? x2 : NEG * x2) + bv[q].z;
            float x3 = s1v + sv[q].w; x3 = (x3 > 0.f ? x3 : NEG * x3) + bv[q].w;
            float p0 = (aw >> (q * 4 + 0)) & 1 ? __expf(x0) : 0.f;
            float p1 = (aw >> (q * 4 + 1)) & 1 ? __expf(x1) : 0.f;
            float p2 = (aw >> (q * 4 + 2)) & 1 ? __expf(x2) : 0.f;
            float p3 = (aw >> (q * 4 + 3)) & 1 ? __expf(x3) : 0.f;
            z_acc += (p0 + p1) + (p2 + p3);
            *(ushort4*)&P[prow][pj0 + q * 4] =
                make_ushort4(f2bf(p0), f2bf(p1), f2bf(p2), f2bf(p3));
        }
    };

    // prologue
    bload(0);
    load_it(0);

    for (int it = 0; it < 16; ++it) {
        const int j0 = it * 64;
        phaseA();                       // LDS writes of B + P (consumes regs)
        __syncthreads();
        if (it < 15) { bload(j0 + 64); load_it(j0 + 64); }   // overlap with MFMA below
        // ---- MFMA phase: A (P) and B (h') fragments from LDS
#pragma unroll
        for (int kw = 0; kw < 2; ++kw) {
            s16x8 a0 = *(const s16x8*)&P[arow0][kw * 32 + koff];
            s16x8 a1 = *(const s16x8*)&P[arow0 + 16][kw * 32 + koff];
#pragma unroll
            for (int fc = 0; fc < 4; ++fc) {
                const int r = wc + fc * 16 + (lane & 15);
                const int chunk = (lane >> 4) + kw * 4;
                s16x8 bf = *(const s16x8*)&Bl[r * 64 + ((chunk ^ (r & 7)) * 8)];
                acc[0][fc] = __builtin_amdgcn_mfma_f32_16x16x32_bf16(a0, bf, acc[0][fc], 0, 0, 0);
                acc[1][fc] = __builtin_amdgcn_mfma_f32_16x16x32_bf16(a1, bf, acc[1][fc], 0, 0, 0);
            }
        }
        __syncthreads();
    }

    // Z: reduce 4 lanes per row (lanes grouped consecutively)
    float z2 = z_acc + __shfl_xor(z_acc, 1);
    float z4 = z2 + __shfl_xor(z2, 2);
    if ((lane & 3) == 0) Zl[prow] = 0.125f / z4;   // folds softmax norm + head-mean
    __syncthreads();

    // epilogue: C/D layout col=lane&15, row=(lane>>4)*4+reg
#pragma unroll
    for (int fr = 0; fr < 2; ++fr) {
#pragma unroll
        for (int r = 0; r < 4; ++r) {
            const int il = wr + fr * 16 + (lane >> 4) * 4 + r;
            const float sc = Zl[il];
            float* op = out + ((size_t)((b << 10) + i0 + il)) * FOUT + wc + (lane & 15);
#pragma unroll
            for (int fc = 0; fc < 4; ++fc)
                unsafeAtomicAdd(op + fc * 16, acc[fr][fc][r] * sc);
        }
    }
}

extern "C" void kernel_launch(void* const* d_in, const int* in_sizes, int n_in,
                              void* d_out, int out_size, void* d_ws, size_t ws_size,
                              hipStream_t stream) {
    const float* hsrc = (const float*)d_in[0];
    const int*   adj  = (const int*)d_in[1];
    const float* bias = (const float*)d_in[2];
    const float* W    = (const float*)d_in[3];
    const float* a    = (const float*)d_in[4];
    float* out = (float*)d_out;

    char* ws = (char*)d_ws;
    unsigned short* hpT = (unsigned short*)ws;                 // 16 MB
    float* s1  = (float*)(ws + 16777216);                      // 256 KB
    float* s2T = s1 + 65536;                                   // 256 KB
    unsigned int* adjbits = (unsigned int*)(s2T + 65536);      // 128 KB
    unsigned short* WT = (unsigned short*)((char*)adjbits + 131072);  // 256 KB

    hipMemsetAsync(d_out, 0, (size_t)out_size * sizeof(float), stream);
    k_pack<<<dim3(N_ * N_ / 256), 256, 0, stream>>>(adj, adjbits);
    k_wt<<<dim3(H_), 256, 0, stream>>>(W, WT);
    k_hprime<<<dim3(B_ * N_ / 64, H_), 256, 0, stream>>>(hsrc, WT, a, hpT, s1, s2T);
    k_pv2<<<dim3(N_ / 64, H_, B_), 256, 0, stream>>>(hpT, s1, s2T, adjbits, bias, out);
}

// Round 7
// 94.319 us; speedup vs baseline: 2.2542x; 1.0971x over previous
//
#include <hip/hip_runtime.h>
#include <hip/hip_bf16.h>
#include <math.h>

#define B_   8
#define N_   1024
#define FIN  128
#define FOUT 128
#define H_   8
#define NEG  0.2f

typedef __attribute__((ext_vector_type(4))) float f32x4;
typedef __attribute__((ext_vector_type(8))) short s16x8;

static __device__ __forceinline__ unsigned short f2bf(float f) {
    unsigned int u = __float_as_uint(f);
    unsigned int r = (u + 0x7fffu + ((u >> 16) & 1u)) >> 16;   // RNE (software)
    return (unsigned short)r;
}

static __device__ __forceinline__ unsigned short f2bf_hw(float f) {
    union { __hip_bfloat16 b; unsigned short u; } cv;
    cv.b = __float2bfloat16(f);
    return cv.u;
}

// ---------------- K0: biasm[i][j] = adj ? bias : -inf  (mask folded into bias) -------
// grid 1024, block 256, 4 elems/thread
__global__ __launch_bounds__(256) void k_bias(const int* __restrict__ adj,
                                              const float* __restrict__ bias,
                                              float* __restrict__ biasm) {
    const int base = (blockIdx.x * 256 + threadIdx.x) * 4;
    int4   av = *(const int4*)&adj[base];
    float4 bv = *(const float4*)&bias[base];
    const float NINF = -__builtin_inff();
    float4 r;
    r.x = av.x ? bv.x : NINF;
    r.y = av.y ? bv.y : NINF;
    r.z = av.z ? bv.z : NINF;
    r.w = av.w ? bv.w : NINF;
    *(float4*)&biasm[base] = r;
}

// ---------------- K0b: W [H][FIN][FOUT] f32  ->  WT [H][FOUT][FIN] bf16 --------------
// grid H, block 256
__global__ __launch_bounds__(256) void k_wt(const float* __restrict__ W,
                                            unsigned short* __restrict__ WT) {
    const int hd = blockIdx.x;
    const int t  = threadIdx.x;
    const int fo  = t >> 1;
    const int fi0 = (t & 1) * 64;
    const float* src = W + (size_t)hd * FIN * FOUT;
    unsigned short* dst = WT + ((size_t)hd * FOUT + fo) * FIN + fi0;
#pragma unroll
    for (int c = 0; c < 8; ++c) {
        s16x8 v;
#pragma unroll
        for (int u = 0; u < 8; ++u)
            v[u] = (short)f2bf(src[(size_t)(fi0 + c * 8 + u) * FOUT + fo]);
        *(s16x8*)(dst + c * 8) = v;
    }
}

// ---------------- K1: h' via bf16 MFMA + transpose-to-bf16 + s1/s2 epilogue ----------
// grid (BN/64, H), block 256 (4 waves, each 16 rows x 128 cols)
#define PADK 132   // shorts; 264B row stride -> balanced b128 reads
union SmemK1 {
    struct {
        unsigned short A[64 * PADK];     // 16896 B  (h tile, bf16)
        unsigned short Bm[128 * PADK];   // 33792 B  (WT tile, bf16)
    } s;                                  // 50688 B
    float tr[64 * PADK];                  // 33792 B  (C f32, [n][f] padded)
};

__global__ __launch_bounds__(256, 3) void k_hprime(const float* __restrict__ hsrc,
                                                   const unsigned short* __restrict__ WT,
                                                   const float* __restrict__ a,
                                                   unsigned short* __restrict__ hpT,
                                                   float* __restrict__ s1,
                                                   float* __restrict__ s2T) {
    __shared__ SmemK1 sm;
    const int t    = threadIdx.x;
    const int lane = t & 63;
    const int wave = t >> 6;
    const int bn0  = blockIdx.x * 64;
    const int hd   = blockIdx.y;

    // ---- stage A: h rows bn0..+63 f32 -> bf16 LDS. thread: row=t>>2, k0=(t&3)*32
    {
        const int r = t >> 2, k0 = (t & 3) * 32;
        const float* src = hsrc + (size_t)(bn0 + r) * FIN + k0;
        unsigned short* dst = &sm.s.A[r * PADK + k0];
#pragma unroll
        for (int c = 0; c < 4; ++c) {
            float4 x = *(const float4*)&src[c * 8];
            float4 y = *(const float4*)&src[c * 8 + 4];
            s16x8 v;
            v[0] = (short)f2bf(x.x); v[1] = (short)f2bf(x.y);
            v[2] = (short)f2bf(x.z); v[3] = (short)f2bf(x.w);
            v[4] = (short)f2bf(y.x); v[5] = (short)f2bf(y.y);
            v[6] = (short)f2bf(y.z); v[7] = (short)f2bf(y.w);
            *(s16x8*)(dst + c * 8) = v;
        }
    }
    // ---- stage B: WT[hd] 128x128 bf16. thread: row=t>>1, k0=(t&1)*64
    {
        const int r = t >> 1, k0 = (t & 1) * 64;
        const unsigned short* src = WT + ((size_t)hd * FOUT + r) * FIN + k0;
        unsigned short* dst = &sm.s.Bm[r * PADK + k0];
#pragma unroll
        for (int c = 0; c < 8; ++c)
            *(s16x8*)(dst + c * 8) = *(const s16x8*)(src + c * 8);
    }
    __syncthreads();

    // ---- MFMA: wave tile 16 rows x 128 cols, K=128
    const int wr   = wave * 16;
    const int arow = wr + (lane & 15);
    const int koff = (lane >> 4) * 8;
    f32x4 acc[8];
#pragma unroll
    for (int fc = 0; fc < 8; ++fc) acc[fc] = (f32x4){0.f, 0.f, 0.f, 0.f};
#pragma unroll
    for (int kk = 0; kk < 4; ++kk) {
        s16x8 av = *(const s16x8*)&sm.s.A[arow * PADK + kk * 32 + koff];
#pragma unroll
        for (int fc = 0; fc < 8; ++fc) {
            s16x8 bv = *(const s16x8*)&sm.s.Bm[(fc * 16 + (lane & 15)) * PADK + kk * 32 + koff];
            acc[fc] = __builtin_amdgcn_mfma_f32_16x16x32_bf16(av, bv, acc[fc], 0, 0, 0);
        }
    }
    __syncthreads();   // done reading A/Bm; reuse union as tr

    // ---- C -> tr[n][f] f32 (C/D layout: col=lane&15, row=(lane>>4)*4+reg)
#pragma unroll
    for (int fc = 0; fc < 8; ++fc)
#pragma unroll
        for (int r = 0; r < 4; ++r)
            sm.tr[(wr + (lane >> 4) * 4 + r) * PADK + fc * 16 + (lane & 15)] = acc[fc][r];
    __syncthreads();

    // ---- transposed bf16 write: thread t: f = t>>1, n-segment (t&1)*32..+31
    {
        const int f   = t >> 1;
        const int seg = (t & 1) * 32;
        const int b   = bn0 >> 10;
        const int n0  = bn0 & 1023;
        unsigned short* dst = hpT + (((size_t)(b * H_ + hd) * FOUT + f) * N_) + n0 + seg;
#pragma unroll
        for (int c = 0; c < 4; ++c) {
            s16x8 v;
#pragma unroll
            for (int u = 0; u < 8; ++u)
                v[u] = (short)f2bf(sm.tr[(seg + c * 8 + u) * PADK + f]);
            *(s16x8*)(dst + c * 8) = v;
        }
    }
    // ---- s1/s2 from exact f32 h': 4 threads per row, 32 f each, shfl reduce
    {
        const int row = t >> 2, f0 = (t & 3) * 32;
        const float* a1 = a + (size_t)hd * 2 * FOUT;
        const float* a2 = a1 + FOUT;
        float v1 = 0.f, v2 = 0.f;
#pragma unroll 8
        for (int fi = 0; fi < 32; ++fi) {
            float hv = sm.tr[row * PADK + f0 + fi];
            v1 += hv * a1[f0 + fi];
            v2 += hv * a2[f0 + fi];
        }
        v1 += __shfl_xor(v1, 1); v1 += __shfl_xor(v1, 2);
        v2 += __shfl_xor(v2, 1); v2 += __shfl_xor(v2, 2);
        if ((t & 3) == 0) {
            int bn = bn0 + row;
            s1[(size_t)bn * 8 + hd]          = v1;
            s2T[(size_t)hd * (B_ * N_) + bn] = v2;
        }
    }
}

// ---------------- K2: fused P-gen + MFMA PV, 32-row tiles, LDS-staged B ----------
// grid (N/32, H, B), block 256 (4 waves, each 16 rows x 64 cols)
__global__ __launch_bounds__(256, 8) void k_pv2(const unsigned short* __restrict__ hpT,
                                                const float* __restrict__ s1,
                                                const float* __restrict__ s2T,
                                                const float* __restrict__ biasm,
                                                float* __restrict__ out) {
    __shared__ __align__(16) unsigned short P[32][72];    // 4.6 KB
    __shared__ __align__(16) unsigned short Bl[128 * 64]; // 16 KB, XOR-swizzled chunks
    __shared__ float Zl[32];
    const int t    = threadIdx.x;
    const int lane = t & 63;
    const int wave = t >> 6;
    const int i0 = blockIdx.x * 32;
    const int hd = blockIdx.y;
    const int b  = blockIdx.z;

    // P-gen assignment: one row per 8 threads, 8 consecutive j each
    const int prow = t >> 3;          // 0..31
    const int pj0  = (t & 7) * 8;     // 0..56
    const int gi   = (b << 10) + i0 + prow;
    const float s1v = s1[(size_t)gi * 8 + hd];
    const float* bm_row = biasm + (size_t)(i0 + prow) * N_;
    const float* s2p    = s2T + (size_t)hd * (B_ * N_) + (b << 10);

    // B staging: thread t covers chunk ids {q*256+t}, id -> (f-row id>>3, chunk id&7)
    const unsigned short* hpS = hpT + (size_t)(b * H_ + hd) * FOUT * N_;
    const int brow = t >> 3;          // base f-row for q=0 (rows 0..31)
    const int bc   = t & 7;           // 16B chunk within 128B j-row

    // wave output tile: 16 rows x 64 cols
    const int wr = (wave & 1) * 16;
    const int wc = (wave >> 1) * 64;
    const int arow = wr + (lane & 15);
    const int koff = (lane >> 4) * 8;

    f32x4 acc[4];
#pragma unroll
    for (int j = 0; j < 4; ++j) acc[j] = (f32x4){0.f, 0.f, 0.f, 0.f};
    float z_acc = 0.f;

    float4 bmv[2], sv[2];
    s16x8 Breg[4];

    auto load_it = [&](int j0) {
#pragma unroll
        for (int q = 0; q < 2; ++q) {
            bmv[q] = *(const float4*)&bm_row[j0 + pj0 + q * 4];
            sv[q]  = *(const float4*)&s2p[j0 + pj0 + q * 4];
        }
    };
    auto bload = [&](int j0) {
#pragma unroll
        for (int q = 0; q < 4; ++q)
            Breg[q] = *(const s16x8*)&hpS[(size_t)(brow + q * 32) * N_ + j0 + bc * 8];
    };
    auto phaseA = [&]() {
        // swizzled LDS write of B tile
#pragma unroll
        for (int q = 0; q < 4; ++q) {
            int row = brow + q * 32;
            *(s16x8*)&Bl[row * 64 + ((bc ^ (row & 7)) * 8)] = Breg[q];
        }
        // P-gen + Z: 8 scores -> one 16B LDS write
        s16x8 pv;
#pragma unroll
        for (int q = 0; q < 2; ++q) {
            float x0 = s1v + sv[q].x; x0 = fmaxf(x0, NEG * x0) + bmv[q].x;
            float x1 = s1v + sv[q].y; x1 = fmaxf(x1, NEG * x1) + bmv[q].y;
            float x2 = s1v + sv[q].z; x2 = fmaxf(x2, NEG * x2) + bmv[q].z;
            float x3 = s1v + sv[q].w; x3 = fmaxf(x3, NEG * x3) + bmv[q].w;
            float p0 = __expf(x0);   // exp(-inf) = 0 handles the adj mask
            float p1 = __expf(x1);
            float p2 = __expf(x2);
            float p3 = __expf(x3);
            z_acc += (p0 + p1) + (p2 + p3);
            pv[q * 4 + 0] = (short)f2bf_hw(p0);
            pv[q * 4 + 1] = (short)f2bf_hw(p1);
            pv[q * 4 + 2] = (short)f2bf_hw(p2);
            pv[q * 4 + 3] = (short)f2bf_hw(p3);
        }
        *(s16x8*)&P[prow][pj0] = pv;
    };

    // prologue
    bload(0);
    load_it(0);

    for (int it = 0; it < 16; ++it) {
        const int j0 = it * 64;
        phaseA();                       // LDS writes of B + P (consumes regs)
        __syncthreads();
        if (it < 15) { bload(j0 + 64); load_it(j0 + 64); }   // overlap with MFMA below
        // ---- MFMA phase: A (P) and B (h') fragments from LDS
#pragma unroll
        for (int kw = 0; kw < 2; ++kw) {
            s16x8 a0 = *(const s16x8*)&P[arow][kw * 32 + koff];
#pragma unroll
            for (int fc = 0; fc < 4; ++fc) {
                const int r = wc + fc * 16 + (lane & 15);
                const int chunk = (lane >> 4) + kw * 4;
                s16x8 bf = *(const s16x8*)&Bl[r * 64 + ((chunk ^ (r & 7)) * 8)];
                acc[fc] = __builtin_amdgcn_mfma_f32_16x16x32_bf16(a0, bf, acc[fc], 0, 0, 0);
            }
        }
        __syncthreads();
    }

    // Z: reduce 8 lanes per row (lanes grouped consecutively)
    float z = z_acc;
    z += __shfl_xor(z, 1); z += __shfl_xor(z, 2); z += __shfl_xor(z, 4);
    if ((t & 7) == 0) Zl[prow] = 0.125f / z;   // folds softmax norm + head-mean
    __syncthreads();

    // epilogue: C/D layout col=lane&15, row=(lane>>4)*4+reg
#pragma unroll
    for (int r = 0; r < 4; ++r) {
        const int il = wr + (lane >> 4) * 4 + r;
        const float sc = Zl[il];
        float* op = out + ((size_t)((b << 10) + i0 + il)) * FOUT + wc + (lane & 15);
#pragma unroll
        for (int fc = 0; fc < 4; ++fc)
            unsafeAtomicAdd(op + fc * 16, acc[fc][r] * sc);
    }
}

extern "C" void kernel_launch(void* const* d_in, const int* in_sizes, int n_in,
                              void* d_out, int out_size, void* d_ws, size_t ws_size,
                              hipStream_t stream) {
    const float* hsrc = (const float*)d_in[0];
    const int*   adj  = (const int*)d_in[1];
    const float* bias = (const float*)d_in[2];
    const float* W    = (const float*)d_in[3];
    const float* a    = (const float*)d_in[4];
    float* out = (float*)d_out;

    char* ws = (char*)d_ws;
    unsigned short* hpT = (unsigned short*)ws;                 // 16 MB
    float* s1    = (float*)(ws + 16777216);                    // 256 KB
    float* s2T   = s1 + 65536;                                 // 256 KB
    float* biasm = s2T + 65536;                                // 4 MB
    unsigned short* WT = (unsigned short*)(biasm + N_ * N_);   // 256 KB

    hipMemsetAsync(d_out, 0, (size_t)out_size * sizeof(float), stream);
    k_bias<<<dim3(N_ * N_ / 1024), 256, 0, stream>>>(adj, bias, biasm);
    k_wt<<<dim3(H_), 256, 0, stream>>>(W, WT);
    k_hprime<<<dim3(B_ * N_ / 64, H_), 256, 0, stream>>>(hsrc, WT, a, hpT, s1, s2T);
    k_pv2<<<dim3(N_ / 32, H_, B_), 256, 0, stream>>>(hpT, s1, s2T, biasm, out);
}